// Round 9
// baseline (448.043 us; speedup 1.0000x reference)
//
#include <hip/hip_runtime.h>

#define NFEAT 128
#define HID 16
#define NOUT 2
#define NGRAPH 64

#define BSH 8                      // bucket shift: 256 nodes/bucket
#define BN 256                     // nodes per bucket
#define NBUCK 391                  // ceil(100000/256)
#define NCB 2048                   // count/scatter chunk blocks (8/CU -> 32 waves/CU)
#define GCNT_TOT (NBUCK * NCB)     // 800768
#define SCAN_NB 782                // scan blocks: 782*1024 >= GCNT_TOT
#define SCAP 18176                 // staged edges per bucket (71 KB)
#define OVR 8                      // register overflow slots/thread
#define PSTRIDE 192                // 128 graph sums + 64 counts
#define GB2 782                    // gather2 blocks = ceil(100000/128)
#define WST 132                    // sWT row stride (floats): 128+4 pad

typedef unsigned short ushortv8 __attribute__((ext_vector_type(8)));

// RNE float -> bf16 bits
__device__ __forceinline__ unsigned short f2bf(float f) {
    unsigned u = __float_as_uint(f);
    return (unsigned short)((u + 0x7FFFu + ((u >> 16) & 1u)) >> 16);
}

// ---------------- count: per-(bucket, chunk) histogram ---------------------
__global__ __launch_bounds__(256) void k_count(const int* __restrict__ dst, int* __restrict__ gcnt, int E) {
    __shared__ int c[NBUCK];
    int t = threadIdx.x;
    for (int i = t; i < NBUCK; i += 256) c[i] = 0;
    __syncthreads();
    int chunk = (E + NCB - 1) / NCB;
    int start = blockIdx.x * chunk;
    int end = min(E, start + chunk);
    for (int e = start + t; e < end; e += 256)
        atomicAdd(&c[dst[e] >> BSH], 1);
    __syncthreads();
    for (int i = t; i < NBUCK; i += 256) gcnt[i * NCB + blockIdx.x] = c[i];
}

// ---------------- scan stage 1: block-local exclusive scan + block sums ----
__global__ __launch_bounds__(1024) void k_scan1(int* __restrict__ gcnt, int* __restrict__ bsum) {
    __shared__ int sh[1024];
    int t = threadIdx.x;
    int idx = blockIdx.x * 1024 + t;
    int v = (idx < GCNT_TOT) ? gcnt[idx] : 0;
    sh[t] = v;
    __syncthreads();
    for (int off = 1; off < 1024; off <<= 1) {
        int a = sh[t];
        int b = (t >= off) ? sh[t - off] : 0;
        __syncthreads();
        sh[t] = a + b;
        __syncthreads();
    }
    if (idx < GCNT_TOT) gcnt[idx] = sh[t] - v;     // exclusive within block
    if (t == 1023) bsum[blockIdx.x] = sh[1023];
}

// ---------------- scan stage 2: scan the 782 block sums --------------------
__global__ __launch_bounds__(1024) void k_scan2(int* __restrict__ bsum) {
    __shared__ int sh[1024];
    int t = threadIdx.x;
    int v = (t < SCAN_NB) ? bsum[t] : 0;
    sh[t] = v;
    __syncthreads();
    for (int off = 1; off < 1024; off <<= 1) {
        int a = sh[t];
        int b = (t >= off) ? sh[t - off] : 0;
        __syncthreads();
        sh[t] = a + b;
        __syncthreads();
    }
    if (t < SCAN_NB) bsum[t] = sh[t] - v;          // exclusive
}

// ---------------- scan stage 3: add block offsets --------------------------
__global__ __launch_bounds__(1024) void k_scan3(int* __restrict__ gcnt, const int* __restrict__ bsum) {
    int idx = blockIdx.x * 1024 + threadIdx.x;
    if (idx < GCNT_TOT) gcnt[idx] += bsum[blockIdx.x];
}

// ---------------- scatter: bucket edges, packed (dloc<<17)|src -------------
__global__ __launch_bounds__(256) void k_scatter(const int* __restrict__ src, const int* __restrict__ dst,
                                                 const int* __restrict__ gcnt,
                                                 unsigned int* __restrict__ bpk, int E) {
    __shared__ int off[NBUCK];
    int t = threadIdx.x;
    for (int i = t; i < NBUCK; i += 256) off[i] = gcnt[i * NCB + blockIdx.x];
    __syncthreads();
    int chunk = (E + NCB - 1) / NCB;
    int start = blockIdx.x * chunk;
    int end = min(E, start + chunk);
    for (int e = start + t; e < end; e += 256) {
        int s = src[e];
        int d = dst[e];
        int kb = d >> BSH;
        int pos = atomicAdd(&off[kb], 1);
        bpk[pos] = ((unsigned)(d & (BN - 1)) << 17) | (unsigned)s;
    }
}

// ---------------- sort: per-bucket counting sort (in place) -> CSR ---------
__global__ __launch_bounds__(1024) void k_sort(unsigned int* __restrict__ bpk, const int* __restrict__ gcnt,
                                               int* __restrict__ rowptr, float* __restrict__ dinv, int E, int N) {
    __shared__ unsigned int stage[SCAP];     // 71 KB
    __shared__ int hist4[4 * BN];            // x4 replicated histogram
    __shared__ int excl[BN], cur[BN];
    int t = threadIdx.x;
    int k = blockIdx.x;
    int bstart = gcnt[k * NCB];
    int bend = (k < NBUCK - 1) ? gcnt[(k + 1) * NCB] : E;
    int len = bend - bstart;
    int nst = min(len, SCAP);
    if (t < 4 * BN) hist4[t] = 0;
    for (int j = t; j < nst; j += 1024) stage[j] = bpk[bstart + j];
    unsigned int ov[OVR];
    int nov = 0;
    for (int j = SCAP + t; j < len; j += 1024)
        if (nov < OVR) ov[nov++] = bpk[bstart + j];
    __syncthreads();
    int rep = (t & 3) << 8;
    for (int j = t; j < nst; j += 1024) atomicAdd(&hist4[rep | (stage[j] >> 17)], 1);
    for (int i = 0; i < nov; i++) atomicAdd(&hist4[rep | (ov[i] >> 17)], 1);
    __syncthreads();
    int hcount = 0;
    if (t < BN) {
        hcount = hist4[t] + hist4[BN + t] + hist4[2 * BN + t] + hist4[3 * BN + t];
        excl[t] = hcount;
    }
    __syncthreads();
    for (int off = 1; off < BN; off <<= 1) {
        int v = 0;
        if (t < BN && t >= off) v = excl[t - off];
        __syncthreads();
        if (t < BN && t >= off) excl[t] += v;
        __syncthreads();
    }
    if (t < BN) {
        int ex = excl[t] - hcount;
        cur[t] = ex;
        int node = (k << BSH) + t;
        rowptr[node] = bstart + ex;
        if (node < N) dinv[node] = 1.0f / sqrtf(1.0f + (float)hcount);
    }
    __syncthreads();
    for (int j = t; j < nst; j += 1024) {
        unsigned int w = stage[j];
        int r = atomicAdd(&cur[w >> 17], 1);
        bpk[bstart + r] = w & 0x1FFFF;
    }
    for (int i = 0; i < nov; i++) {
        unsigned int w = ov[i];
        int r = atomicAdd(&cur[w >> 17], 1);
        bpk[bstart + r] = w & 0x1FFFF;
    }
}

// ---------------- h1b = bf16( dinv * (x @ W1) ) ----------------------------
__global__ __launch_bounds__(256) void k_xw1(const float* __restrict__ x, const float* __restrict__ W1,
                                             const float* __restrict__ dinv,
                                             unsigned short* __restrict__ h1b, int N) {
    __shared__ float sWT[HID * WST];     // transposed + padded: [h][k], stride 132
    __shared__ float sx[16 * 132];
    int t = threadIdx.x;
    for (int i = t; i < HID * NFEAT; i += 256) {
        int h = i >> 7, kk = i & 127;
        sWT[h * WST + kk] = W1[kk * HID + h];
    }
    int local = t >> 4;
    int h     = t & 15;
    int n = blockIdx.x * 16 + local;
    if (n < N) {
        const float4* xr = (const float4*)(x + (size_t)n * NFEAT);
        float4 a = xr[h * 2];
        float4 b = xr[h * 2 + 1];
        float* sp = sx + local * 132 + h * 8;
        ((float4*)sp)[0] = a;
        ((float4*)sp)[1] = b;
    }
    __syncthreads();
    if (n >= N) return;
    const float4* xr4 = (const float4*)(sx + local * 132);
    const float4* wr4 = (const float4*)(sWT + h * WST);
    float acc = 0.0f;
    #pragma unroll
    for (int k4 = 0; k4 < 32; k4++) {
        float4 a = xr4[k4];
        float4 b = wr4[k4];
        acc += a.x * b.x + a.y * b.y + a.z * b.z + a.w * b.w;
    }
    h1b[(size_t)n * HID + h] = f2bf(acc * dinv[n]);   // coalesced 2B/lane
}

__device__ __forceinline__ void acc8(float* acc, ushortv8 v) {
    #pragma unroll
    for (int i = 0; i < 8; i++)
        acc[i] += __uint_as_float(((unsigned)v[i]) << 16);
}

// ---------------- gather1: CSR bf16 gather -> PReLU -> W2 -> t2s -----------
// 2 lanes per node, 16B (8 bf16 feats) each; h1b table is 3.2MB -> L2-resident
__global__ __launch_bounds__(256) void k_gather1(const int* __restrict__ esrc, const int* __restrict__ rowptr,
                                                 const unsigned short* __restrict__ h1b, const float* __restrict__ dinv,
                                                 const float* __restrict__ b1, const float* __restrict__ prelu_a,
                                                 const float* __restrict__ W2,
                                                 float* __restrict__ t2s, int N) {
    int t = threadIdx.x;
    int n = blockIdx.x * 128 + (t >> 1);
    int q = t & 1;
    if (n >= N) return;
    const ushortv8* h8 = (const ushortv8*)h1b;     // 16B granules; row n half q = n*2+q
    int r0 = rowptr[n];
    int r1 = rowptr[n + 1];
    float acc[8] = {0.f, 0.f, 0.f, 0.f, 0.f, 0.f, 0.f, 0.f};
    acc8(acc, h8[(size_t)n * 2 + q]);              // self-loop seed
    int i = r0;
    for (; i + 4 <= r1; i += 4) {
        int s0 = esrc[i], s1 = esrc[i + 1], s2 = esrc[i + 2], s3 = esrc[i + 3];
        ushortv8 v0 = h8[(size_t)s0 * 2 + q];
        ushortv8 v1 = h8[(size_t)s1 * 2 + q];
        ushortv8 v2 = h8[(size_t)s2 * 2 + q];
        ushortv8 v3 = h8[(size_t)s3 * 2 + q];
        acc8(acc, v0); acc8(acc, v1); acc8(acc, v2); acc8(acc, v3);
    }
    for (; i < r1; i++) acc8(acc, h8[(size_t)esrc[i] * 2 + q]);

    float di = dinv[n];
    float a = prelu_a[0];
    float o0 = 0.0f, o1 = 0.0f;
    #pragma unroll
    for (int j = 0; j < 8; j++) {
        int f = q * 8 + j;
        float tv = di * acc[j] + b1[f];
        tv = (tv >= 0.0f) ? tv : a * tv;
        o0 += tv * W2[f * 2 + 0];
        o1 += tv * W2[f * 2 + 1];
    }
    o0 += __shfl_xor(o0, 1);
    o1 += __shfl_xor(o1, 1);
    if (q == 0) {
        *(float2*)(t2s + (size_t)n * 2) = make_float2(di * o0, di * o1);
    }
}

// ---------------- gather2 + pool: CSR sum of t2s -> per-graph bins ---------
__global__ __launch_bounds__(256) void k_gather2(const int* __restrict__ esrc, const int* __restrict__ rowptr,
                                                 const float* __restrict__ t2s, const float* __restrict__ dinv,
                                                 const int* __restrict__ batch,
                                                 float* __restrict__ partials, int N) {
    __shared__ float pg[PSTRIDE];
    int t = threadIdx.x;
    if (t < PSTRIDE) pg[t] = 0.0f;
    __syncthreads();
    int n = blockIdx.x * 128 + (t >> 1);
    int c = t & 1;
    if (n < N) {
        int r0 = rowptr[n];
        int r1 = rowptr[n + 1];
        float val = t2s[(size_t)n * 2 + c];    // self-loop
        int i = r0;
        for (; i + 4 <= r1; i += 4) {
            int s0 = esrc[i], s1 = esrc[i + 1], s2 = esrc[i + 2], s3 = esrc[i + 3];
            float v0 = t2s[(size_t)s0 * 2 + c];
            float v1 = t2s[(size_t)s1 * 2 + c];
            float v2 = t2s[(size_t)s2 * 2 + c];
            float v3 = t2s[(size_t)s3 * 2 + c];
            val += (v0 + v1) + (v2 + v3);
        }
        for (; i < r1; i++) val += t2s[(size_t)esrc[i] * 2 + c];
        float dd = dinv[n];
        int g = batch[n];
        atomicAdd(&pg[g * 2 + c], dd * val);
        if (c == 0) atomicAdd(&pg[128 + g], 1.0f);
    }
    __syncthreads();
    if (t < PSTRIDE) partials[(size_t)blockIdx.x * PSTRIDE + t] = pg[t];
}

// ---------------- final: reduce partials, add bias, divide -----------------
__global__ __launch_bounds__(256) void k_final(const float* __restrict__ partials,
                                               const float* __restrict__ b2, float* __restrict__ out) {
    __shared__ float fs[PSTRIDE];
    int t = threadIdx.x;
    if (t < PSTRIDE) {
        float s0 = 0.0f, s1 = 0.0f, s2 = 0.0f, s3 = 0.0f;
        int r = 0;
        for (; r + 4 <= GB2; r += 4) {
            s0 += partials[(size_t)r * PSTRIDE + t];
            s1 += partials[(size_t)(r + 1) * PSTRIDE + t];
            s2 += partials[(size_t)(r + 2) * PSTRIDE + t];
            s3 += partials[(size_t)(r + 3) * PSTRIDE + t];
        }
        for (; r < GB2; r++) s0 += partials[(size_t)r * PSTRIDE + t];
        fs[t] = (s0 + s1) + (s2 + s3);
    }
    __syncthreads();
    if (t < NGRAPH * NOUT) {
        int g = t >> 1, c = t & 1;
        float cnt = fs[128 + g];
        out[t] = (fs[t] + cnt * b2[c]) / fmaxf(cnt, 1.0f);
    }
}

extern "C" void kernel_launch(void* const* d_in, const int* in_sizes, int n_in,
                              void* d_out, int out_size, void* d_ws, size_t ws_size,
                              hipStream_t stream) {
    const float* x       = (const float*)d_in[0];
    const float* W1      = (const float*)d_in[1];
    const float* b1      = (const float*)d_in[2];
    const float* prelu_a = (const float*)d_in[3];
    const float* W2      = (const float*)d_in[4];
    const float* b2      = (const float*)d_in[5];
    const int*   ei      = (const int*)d_in[6];
    const int*   batch   = (const int*)d_in[7];

    const int N = in_sizes[7];          // 100000
    const int E = in_sizes[6] / 2;      // 6400000
    const int* src = ei;
    const int* dst = ei + E;

    // workspace layout (4-byte units), ~34 MB total
    float* ws     = (float*)d_ws;
    float* dinv   = ws;                                        // 100352
    unsigned short* h1b = (unsigned short*)(dinv + 100352);    // 16N ushorts (= 8N floats)
    float* t2s    = dinv + 100352 + (size_t)N * HID / 2;       // 2N
    int*   rowptr = (int*)(t2s + (size_t)N * NOUT);            // 100352
    int*   gcnt   = rowptr + 100352;                           // GCNT_TOT (3.2 MB)
    unsigned int* bpk = (unsigned int*)(gcnt + GCNT_TOT);      // E (becomes esrc)
    float* partials = (float*)(bpk + E);                       // GB2*PSTRIDE
    int*   bsum   = (int*)(partials + (size_t)GB2 * PSTRIDE);  // SCAN_NB

    float* out = (float*)d_out;

    k_count<<<NCB, 256, 0, stream>>>(dst, gcnt, E);
    k_scan1<<<SCAN_NB, 1024, 0, stream>>>(gcnt, bsum);
    k_scan2<<<1, 1024, 0, stream>>>(bsum);
    k_scan3<<<SCAN_NB, 1024, 0, stream>>>(gcnt, bsum);
    k_scatter<<<NCB, 256, 0, stream>>>(src, dst, gcnt, bpk, E);
    k_sort<<<NBUCK, 1024, 0, stream>>>(bpk, gcnt, rowptr, dinv, E, N);
    k_xw1<<<(N + 15) / 16, 256, 0, stream>>>(x, W1, dinv, h1b, N);
    k_gather1<<<(N + 127) / 128, 256, 0, stream>>>((const int*)bpk, rowptr, h1b, dinv, b1, prelu_a, W2, t2s, N);
    k_gather2<<<GB2, 256, 0, stream>>>((const int*)bpk, rowptr, t2s, dinv, batch, partials, N);
    k_final<<<1, 256, 0, stream>>>(partials, b2, out);
}

// Round 10
// 397.002 us; speedup vs baseline: 1.1286x; 1.1286x over previous
//
#include <hip/hip_runtime.h>

#define NFEAT 128
#define HID 16
#define NOUT 2
#define NGRAPH 64

#define BSH 8                      // bucket shift: 256 nodes/bucket
#define BN 256                     // nodes per bucket
#define NBUCK 391                  // ceil(100000/256)
#define NCB 512                    // count/scatter chunks (1024-thr blocks, 2/CU)
#define GCNT_TOT (NBUCK * NCB)     // 200192
#define SCAN_NB 196                // scan blocks: 196*1024 >= GCNT_TOT
#define SCAP 18176                 // staged edges per bucket (71 KB)
#define OVR 8                      // register overflow slots/thread
#define PSTRIDE 192                // 128 graph sums + 64 counts
#define GB2 782                    // gather2 blocks = ceil(100000/128)
#define WST 132                    // sWT row stride (floats): 128+4 pad

typedef unsigned short ushortv8 __attribute__((ext_vector_type(8)));

// RNE float -> bf16 bits
__device__ __forceinline__ unsigned short f2bf(float f) {
    unsigned u = __float_as_uint(f);
    return (unsigned short)((u + 0x7FFFu + ((u >> 16) & 1u)) >> 16);
}

// ---------------- count: per-(bucket, chunk) histogram ---------------------
__global__ __launch_bounds__(1024) void k_count(const int* __restrict__ dst, int* __restrict__ gcnt, int E) {
    __shared__ int c[NBUCK];
    int t = threadIdx.x;
    for (int i = t; i < NBUCK; i += 1024) c[i] = 0;
    __syncthreads();
    int chunk = (E + NCB - 1) / NCB;
    int start = blockIdx.x * chunk;
    int end = min(E, start + chunk);
    for (int e = start + t; e < end; e += 1024)
        atomicAdd(&c[dst[e] >> BSH], 1);
    __syncthreads();
    for (int i = t; i < NBUCK; i += 1024) gcnt[i * NCB + blockIdx.x] = c[i];
}

// ---------------- scan stage 1: block-local exclusive scan + block sums ----
__global__ __launch_bounds__(1024) void k_scan1(int* __restrict__ gcnt, int* __restrict__ bsum) {
    __shared__ int sh[1024];
    int t = threadIdx.x;
    int idx = blockIdx.x * 1024 + t;
    int v = (idx < GCNT_TOT) ? gcnt[idx] : 0;
    sh[t] = v;
    __syncthreads();
    for (int off = 1; off < 1024; off <<= 1) {
        int a = sh[t];
        int b = (t >= off) ? sh[t - off] : 0;
        __syncthreads();
        sh[t] = a + b;
        __syncthreads();
    }
    if (idx < GCNT_TOT) gcnt[idx] = sh[t] - v;     // exclusive within block
    if (t == 1023) bsum[blockIdx.x] = sh[1023];
}

// ---------------- scan stage 2: scan the 196 block sums --------------------
__global__ __launch_bounds__(256) void k_scan2(int* __restrict__ bsum) {
    __shared__ int sh[256];
    int t = threadIdx.x;
    int v = (t < SCAN_NB) ? bsum[t] : 0;
    sh[t] = v;
    __syncthreads();
    for (int off = 1; off < 256; off <<= 1) {
        int a = sh[t];
        int b = (t >= off) ? sh[t - off] : 0;
        __syncthreads();
        sh[t] = a + b;
        __syncthreads();
    }
    if (t < SCAN_NB) bsum[t] = sh[t] - v;          // exclusive
}

// ---------------- scan stage 3: add block offsets --------------------------
__global__ __launch_bounds__(1024) void k_scan3(int* __restrict__ gcnt, const int* __restrict__ bsum) {
    int idx = blockIdx.x * 1024 + threadIdx.x;
    if (idx < GCNT_TOT) gcnt[idx] += bsum[blockIdx.x];
}

// ---------------- scatter: bucket edges, packed (dloc<<17)|src -------------
// 1024-thr blocks: 32 waves/CU latency hiding; ~128B/bucket region per block
__global__ __launch_bounds__(1024) void k_scatter(const int* __restrict__ src, const int* __restrict__ dst,
                                                  const int* __restrict__ gcnt,
                                                  unsigned int* __restrict__ bpk, int E) {
    __shared__ int off[NBUCK];
    int t = threadIdx.x;
    for (int i = t; i < NBUCK; i += 1024) off[i] = gcnt[i * NCB + blockIdx.x];
    __syncthreads();
    int chunk = (E + NCB - 1) / NCB;
    int start = blockIdx.x * chunk;
    int end = min(E, start + chunk);
    for (int e = start + t; e < end; e += 1024) {
        int s = src[e];
        int d = dst[e];
        int kb = d >> BSH;
        int pos = atomicAdd(&off[kb], 1);
        bpk[pos] = ((unsigned)(d & (BN - 1)) << 17) | (unsigned)s;
    }
}

// ---------------- sort: per-bucket counting sort (in place) -> CSR ---------
__global__ __launch_bounds__(1024) void k_sort(unsigned int* __restrict__ bpk, const int* __restrict__ gcnt,
                                               int* __restrict__ rowptr, float* __restrict__ dinv, int E, int N) {
    __shared__ unsigned int stage[SCAP];     // 71 KB
    __shared__ int hist4[4 * BN];            // x4 replicated histogram
    __shared__ int excl[BN], cur[BN];
    int t = threadIdx.x;
    int k = blockIdx.x;
    int bstart = gcnt[k * NCB];
    int bend = (k < NBUCK - 1) ? gcnt[(k + 1) * NCB] : E;
    int len = bend - bstart;
    int nst = min(len, SCAP);
    if (t < 4 * BN) hist4[t] = 0;
    for (int j = t; j < nst; j += 1024) stage[j] = bpk[bstart + j];
    unsigned int ov[OVR];
    int nov = 0;
    for (int j = SCAP + t; j < len; j += 1024)
        if (nov < OVR) ov[nov++] = bpk[bstart + j];
    __syncthreads();
    int rep = (t & 3) << 8;
    for (int j = t; j < nst; j += 1024) atomicAdd(&hist4[rep | (stage[j] >> 17)], 1);
    for (int i = 0; i < nov; i++) atomicAdd(&hist4[rep | (ov[i] >> 17)], 1);
    __syncthreads();
    int hcount = 0;
    if (t < BN) {
        hcount = hist4[t] + hist4[BN + t] + hist4[2 * BN + t] + hist4[3 * BN + t];
        excl[t] = hcount;
    }
    __syncthreads();
    for (int off = 1; off < BN; off <<= 1) {
        int v = 0;
        if (t < BN && t >= off) v = excl[t - off];
        __syncthreads();
        if (t < BN && t >= off) excl[t] += v;
        __syncthreads();
    }
    if (t < BN) {
        int ex = excl[t] - hcount;
        cur[t] = ex;
        int node = (k << BSH) + t;
        rowptr[node] = bstart + ex;
        if (node < N) dinv[node] = 1.0f / sqrtf(1.0f + (float)hcount);
    }
    __syncthreads();
    for (int j = t; j < nst; j += 1024) {
        unsigned int w = stage[j];
        int r = atomicAdd(&cur[w >> 17], 1);
        bpk[bstart + r] = w & 0x1FFFF;
    }
    for (int i = 0; i < nov; i++) {
        unsigned int w = ov[i];
        int r = atomicAdd(&cur[w >> 17], 1);
        bpk[bstart + r] = w & 0x1FFFF;
    }
}

// ---------------- h1b = bf16( dinv * (x @ W1) ) ----------------------------
__global__ __launch_bounds__(256) void k_xw1(const float* __restrict__ x, const float* __restrict__ W1,
                                             const float* __restrict__ dinv,
                                             unsigned short* __restrict__ h1b, int N) {
    __shared__ float sWT[HID * WST];     // transposed + padded: [h][k], stride 132
    __shared__ float sx[16 * 132];
    int t = threadIdx.x;
    for (int i = t; i < HID * NFEAT; i += 256) {
        int h = i >> 7, kk = i & 127;
        sWT[h * WST + kk] = W1[kk * HID + h];
    }
    int local = t >> 4;
    int h     = t & 15;
    int n = blockIdx.x * 16 + local;
    if (n < N) {
        const float4* xr = (const float4*)(x + (size_t)n * NFEAT);
        float4 a = xr[h * 2];
        float4 b = xr[h * 2 + 1];
        float* sp = sx + local * 132 + h * 8;
        ((float4*)sp)[0] = a;
        ((float4*)sp)[1] = b;
    }
    __syncthreads();
    if (n >= N) return;
    const float4* xr4 = (const float4*)(sx + local * 132);
    const float4* wr4 = (const float4*)(sWT + h * WST);
    float acc = 0.0f;
    #pragma unroll
    for (int k4 = 0; k4 < 32; k4++) {
        float4 a = xr4[k4];
        float4 b = wr4[k4];
        acc += a.x * b.x + a.y * b.y + a.z * b.z + a.w * b.w;
    }
    h1b[(size_t)n * HID + h] = f2bf(acc * dinv[n]);   // coalesced 2B/lane
}

__device__ __forceinline__ void acc8(float* acc, ushortv8 v) {
    #pragma unroll
    for (int i = 0; i < 8; i++)
        acc[i] += __uint_as_float(((unsigned)v[i]) << 16);
}

// ---------------- gather1: CSR bf16 gather -> PReLU -> W2 -> t2s -----------
// 2 lanes per node, 16B (8 bf16 feats) each; h1b table is 3.2MB -> L2-resident
__global__ __launch_bounds__(256) void k_gather1(const int* __restrict__ esrc, const int* __restrict__ rowptr,
                                                 const unsigned short* __restrict__ h1b, const float* __restrict__ dinv,
                                                 const float* __restrict__ b1, const float* __restrict__ prelu_a,
                                                 const float* __restrict__ W2,
                                                 float* __restrict__ t2s, int N) {
    int t = threadIdx.x;
    int n = blockIdx.x * 128 + (t >> 1);
    int q = t & 1;
    if (n >= N) return;
    const ushortv8* h8 = (const ushortv8*)h1b;     // 16B granules; row n half q = n*2+q
    int r0 = rowptr[n];
    int r1 = rowptr[n + 1];
    float acc[8] = {0.f, 0.f, 0.f, 0.f, 0.f, 0.f, 0.f, 0.f};
    acc8(acc, h8[(size_t)n * 2 + q]);              // self-loop seed
    int i = r0;
    for (; i + 4 <= r1; i += 4) {
        int s0 = esrc[i], s1 = esrc[i + 1], s2 = esrc[i + 2], s3 = esrc[i + 3];
        ushortv8 v0 = h8[(size_t)s0 * 2 + q];
        ushortv8 v1 = h8[(size_t)s1 * 2 + q];
        ushortv8 v2 = h8[(size_t)s2 * 2 + q];
        ushortv8 v3 = h8[(size_t)s3 * 2 + q];
        acc8(acc, v0); acc8(acc, v1); acc8(acc, v2); acc8(acc, v3);
    }
    for (; i < r1; i++) acc8(acc, h8[(size_t)esrc[i] * 2 + q]);

    float di = dinv[n];
    float a = prelu_a[0];
    float o0 = 0.0f, o1 = 0.0f;
    #pragma unroll
    for (int j = 0; j < 8; j++) {
        int f = q * 8 + j;
        float tv = di * acc[j] + b1[f];
        tv = (tv >= 0.0f) ? tv : a * tv;
        o0 += tv * W2[f * 2 + 0];
        o1 += tv * W2[f * 2 + 1];
    }
    o0 += __shfl_xor(o0, 1);
    o1 += __shfl_xor(o1, 1);
    if (q == 0) {
        *(float2*)(t2s + (size_t)n * 2) = make_float2(di * o0, di * o1);
    }
}

// ---------------- gather2 + pool: CSR sum of t2s -> per-graph bins ---------
__global__ __launch_bounds__(256) void k_gather2(const int* __restrict__ esrc, const int* __restrict__ rowptr,
                                                 const float* __restrict__ t2s, const float* __restrict__ dinv,
                                                 const int* __restrict__ batch,
                                                 float* __restrict__ partials, int N) {
    __shared__ float pg[PSTRIDE];
    int t = threadIdx.x;
    if (t < PSTRIDE) pg[t] = 0.0f;
    __syncthreads();
    int n = blockIdx.x * 128 + (t >> 1);
    int c = t & 1;
    if (n < N) {
        int r0 = rowptr[n];
        int r1 = rowptr[n + 1];
        float val = t2s[(size_t)n * 2 + c];    // self-loop
        int i = r0;
        for (; i + 4 <= r1; i += 4) {
            int s0 = esrc[i], s1 = esrc[i + 1], s2 = esrc[i + 2], s3 = esrc[i + 3];
            float v0 = t2s[(size_t)s0 * 2 + c];
            float v1 = t2s[(size_t)s1 * 2 + c];
            float v2 = t2s[(size_t)s2 * 2 + c];
            float v3 = t2s[(size_t)s3 * 2 + c];
            val += (v0 + v1) + (v2 + v3);
        }
        for (; i < r1; i++) val += t2s[(size_t)esrc[i] * 2 + c];
        float dd = dinv[n];
        int g = batch[n];
        atomicAdd(&pg[g * 2 + c], dd * val);
        if (c == 0) atomicAdd(&pg[128 + g], 1.0f);
    }
    __syncthreads();
    if (t < PSTRIDE) partials[(size_t)blockIdx.x * PSTRIDE + t] = pg[t];
}

// ---------------- final: reduce partials, add bias, divide -----------------
__global__ __launch_bounds__(256) void k_final(const float* __restrict__ partials,
                                               const float* __restrict__ b2, float* __restrict__ out) {
    __shared__ float fs[PSTRIDE];
    int t = threadIdx.x;
    if (t < PSTRIDE) {
        float s0 = 0.0f, s1 = 0.0f, s2 = 0.0f, s3 = 0.0f;
        int r = 0;
        for (; r + 4 <= GB2; r += 4) {
            s0 += partials[(size_t)r * PSTRIDE + t];
            s1 += partials[(size_t)(r + 1) * PSTRIDE + t];
            s2 += partials[(size_t)(r + 2) * PSTRIDE + t];
            s3 += partials[(size_t)(r + 3) * PSTRIDE + t];
        }
        for (; r < GB2; r++) s0 += partials[(size_t)r * PSTRIDE + t];
        fs[t] = (s0 + s1) + (s2 + s3);
    }
    __syncthreads();
    if (t < NGRAPH * NOUT) {
        int g = t >> 1, c = t & 1;
        float cnt = fs[128 + g];
        out[t] = (fs[t] + cnt * b2[c]) / fmaxf(cnt, 1.0f);
    }
}

extern "C" void kernel_launch(void* const* d_in, const int* in_sizes, int n_in,
                              void* d_out, int out_size, void* d_ws, size_t ws_size,
                              hipStream_t stream) {
    const float* x       = (const float*)d_in[0];
    const float* W1      = (const float*)d_in[1];
    const float* b1      = (const float*)d_in[2];
    const float* prelu_a = (const float*)d_in[3];
    const float* W2      = (const float*)d_in[4];
    const float* b2      = (const float*)d_in[5];
    const int*   ei      = (const int*)d_in[6];
    const int*   batch   = (const int*)d_in[7];

    const int N = in_sizes[7];          // 100000
    const int E = in_sizes[6] / 2;      // 6400000
    const int* src = ei;
    const int* dst = ei + E;

    // workspace layout (4-byte units), ~31 MB total
    float* ws     = (float*)d_ws;
    float* dinv   = ws;                                        // 100352
    unsigned short* h1b = (unsigned short*)(dinv + 100352);    // 16N ushorts (= 8N floats)
    float* t2s    = dinv + 100352 + (size_t)N * HID / 2;       // 2N
    int*   rowptr = (int*)(t2s + (size_t)N * NOUT);            // 100352
    int*   gcnt   = rowptr + 100352;                           // GCNT_TOT (800 KB)
    unsigned int* bpk = (unsigned int*)(gcnt + GCNT_TOT);      // E (becomes esrc)
    float* partials = (float*)(bpk + E);                       // GB2*PSTRIDE
    int*   bsum   = (int*)(partials + (size_t)GB2 * PSTRIDE);  // SCAN_NB

    float* out = (float*)d_out;

    k_count<<<NCB, 1024, 0, stream>>>(dst, gcnt, E);
    k_scan1<<<SCAN_NB, 1024, 0, stream>>>(gcnt, bsum);
    k_scan2<<<1, 256, 0, stream>>>(bsum);
    k_scan3<<<SCAN_NB, 1024, 0, stream>>>(gcnt, bsum);
    k_scatter<<<NCB, 1024, 0, stream>>>(src, dst, gcnt, bpk, E);
    k_sort<<<NBUCK, 1024, 0, stream>>>(bpk, gcnt, rowptr, dinv, E, N);
    k_xw1<<<(N + 15) / 16, 256, 0, stream>>>(x, W1, dinv, h1b, N);
    k_gather1<<<(N + 127) / 128, 256, 0, stream>>>((const int*)bpk, rowptr, h1b, dinv, b1, prelu_a, W2, t2s, N);
    k_gather2<<<GB2, 256, 0, stream>>>((const int*)bpk, rowptr, t2s, dinv, batch, partials, N);
    k_final<<<1, 256, 0, stream>>>(partials, b2, out);
}

// Round 11
// 346.151 us; speedup vs baseline: 1.2944x; 1.1469x over previous
//
#include <hip/hip_runtime.h>

#define NFEAT 128
#define HID 16
#define NOUT 2
#define NGRAPH 64

#define BSH 8                      // bucket shift: 256 nodes/bucket
#define BN 256                     // nodes per bucket
#define NBUCK 391                  // ceil(100000/256)
#define NCB 512                    // count/scatter chunks (1024-thr blocks, 2/CU)
#define CH 12500                   // chunk length = E/NCB exactly
#define EPT 13                     // edges per thread (13*1024 >= 12500)
#define GCNT_TOT (NBUCK * NCB)     // 200192
#define SCAN_NB 196                // scan blocks: 196*1024 >= GCNT_TOT
#define SCAP 18176                 // k_sort staged edges per bucket (71 KB)
#define OVR 8                      // k_sort register overflow slots/thread
#define PSTRIDE 192                // 128 graph sums + 64 counts
#define GB2 782                    // gather2 blocks = ceil(100000/128)
#define WST 132                    // sWT row stride (floats): 128+4 pad

typedef unsigned short ushortv8 __attribute__((ext_vector_type(8)));

// XCD-aware chunk remap: consecutive chunks stay on one XCD (8 XCDs, rr dispatch)
__device__ __forceinline__ int chunk_id(int bid) { return ((bid & 7) << 6) | (bid >> 3); }

// RNE float -> bf16 bits
__device__ __forceinline__ unsigned short f2bf(float f) {
    unsigned u = __float_as_uint(f);
    return (unsigned short)((u + 0x7FFFu + ((u >> 16) & 1u)) >> 16);
}

// ---------------- count: per-(bucket, chunk) histogram ---------------------
__global__ __launch_bounds__(1024) void k_count(const int* __restrict__ dst, int* __restrict__ gcnt, int E) {
    __shared__ int c[NBUCK];
    int t = threadIdx.x;
    int cid = chunk_id(blockIdx.x);
    for (int i = t; i < NBUCK; i += 1024) c[i] = 0;
    __syncthreads();
    int start = cid * CH;
    int end = min(E, start + CH);
    for (int e = start + t; e < end; e += 1024)
        atomicAdd(&c[dst[e] >> BSH], 1);
    __syncthreads();
    for (int i = t; i < NBUCK; i += 1024) gcnt[i * NCB + cid] = c[i];
}

// ---------------- scan stage 1: block-local exclusive scan + block sums ----
__global__ __launch_bounds__(1024) void k_scan1(int* __restrict__ gcnt, int* __restrict__ bsum) {
    __shared__ int sh[1024];
    int t = threadIdx.x;
    int idx = blockIdx.x * 1024 + t;
    int v = (idx < GCNT_TOT) ? gcnt[idx] : 0;
    sh[t] = v;
    __syncthreads();
    for (int off = 1; off < 1024; off <<= 1) {
        int a = sh[t];
        int b = (t >= off) ? sh[t - off] : 0;
        __syncthreads();
        sh[t] = a + b;
        __syncthreads();
    }
    if (idx < GCNT_TOT) gcnt[idx] = sh[t] - v;     // exclusive within block
    if (t == 1023) bsum[blockIdx.x] = sh[1023];
}

// ---------------- scan stage 2: scan the 196 block sums --------------------
__global__ __launch_bounds__(256) void k_scan2(int* __restrict__ bsum) {
    __shared__ int sh[256];
    int t = threadIdx.x;
    int v = (t < SCAN_NB) ? bsum[t] : 0;
    sh[t] = v;
    __syncthreads();
    for (int off = 1; off < 256; off <<= 1) {
        int a = sh[t];
        int b = (t >= off) ? sh[t - off] : 0;
        __syncthreads();
        sh[t] = a + b;
        __syncthreads();
    }
    if (t < SCAN_NB) bsum[t] = sh[t] - v;          // exclusive
}

// ---------------- scan stage 3: add block offsets --------------------------
__global__ __launch_bounds__(1024) void k_scan3(int* __restrict__ gcnt, const int* __restrict__ bsum) {
    int idx = blockIdx.x * 1024 + threadIdx.x;
    if (idx < GCNT_TOT) gcnt[idx] += bsum[blockIdx.x];
}

// ---------------- scatter: LDS-staged local sort by bucket, burst flush ----
__global__ __launch_bounds__(1024) void k_scatter(const int* __restrict__ src, const int* __restrict__ dst,
                                                  const int* __restrict__ gcnt,
                                                  unsigned int* __restrict__ bpk, int E) {
    __shared__ unsigned int stage[CH + 44];  // 50176 B
    __shared__ int hist4[4 * NBUCK];         // 6256 B
    __shared__ int scan[512];                // 2048 B
    __shared__ int excl[NBUCK + 1];
    __shared__ int cur[NBUCK];
    int t = threadIdx.x;
    int cid = chunk_id(blockIdx.x);
    int start = cid * CH;
    int end = min(E, start + CH);
    for (int i = t; i < 4 * NBUCK; i += 1024) hist4[i] = 0;
    __syncthreads();

    // phase 1: load into registers, histogram
    unsigned int w[EPT];
    int kb[EPT];
    int rep = (t & 3) * NBUCK;
    #pragma unroll
    for (int i = 0; i < EPT; i++) {
        int e = start + i * 1024 + t;
        kb[i] = -1;
        if (e < end) {
            int s = src[e];
            int d = dst[e];
            int b = d >> BSH;
            kb[i] = b;
            w[i] = ((unsigned)(d & (BN - 1)) << 17) | (unsigned)s;
            atomicAdd(&hist4[rep + b], 1);
        }
    }
    __syncthreads();

    // phase 2: scan 391 bucket counts (512-wide Hillis-Steele)
    int hc = 0;
    if (t < NBUCK) hc = hist4[t] + hist4[NBUCK + t] + hist4[2 * NBUCK + t] + hist4[3 * NBUCK + t];
    if (t < 512) scan[t] = (t < NBUCK) ? hc : 0;
    __syncthreads();
    for (int off = 1; off < 512; off <<= 1) {
        int a = 0;
        if (t < 512 && t >= off) a = scan[t - off];
        __syncthreads();
        if (t < 512 && t >= off) scan[t] += a;
        __syncthreads();
    }
    if (t < NBUCK) {
        int ex = scan[t] - hc;
        excl[t] = ex;
        cur[t] = ex;
    }
    if (t == 0) excl[NBUCK] = end - start;
    __syncthreads();

    // phase 3: rank into bucket-ordered LDS stage
    #pragma unroll
    for (int i = 0; i < EPT; i++) {
        if (kb[i] >= 0) {
            int r = atomicAdd(&cur[kb[i]], 1);
            stage[r] = w[i];
        }
    }
    __syncthreads();

    // phase 4: burst flush, one wave per bucket run (contiguous global writes)
    int wave = t >> 6, lane = t & 63;
    for (int b = wave; b < NBUCK; b += 16) {
        int s0 = excl[b], s1 = excl[b + 1];
        int gbase = gcnt[b * NCB + cid];
        for (int j = s0 + lane; j < s1; j += 64)
            bpk[gbase + (j - s0)] = stage[j];
    }
}

// ---------------- sort: per-bucket counting sort (in place) -> CSR ---------
__global__ __launch_bounds__(1024) void k_sort(unsigned int* __restrict__ bpk, const int* __restrict__ gcnt,
                                               int* __restrict__ rowptr, float* __restrict__ dinv, int E, int N) {
    __shared__ unsigned int stage[SCAP];     // 71 KB
    __shared__ int hist4[4 * BN];            // x4 replicated histogram
    __shared__ int excl[BN], cur[BN];
    int t = threadIdx.x;
    int k = blockIdx.x;
    int bstart = gcnt[k * NCB];
    int bend = (k < NBUCK - 1) ? gcnt[(k + 1) * NCB] : E;
    int len = bend - bstart;
    int nst = min(len, SCAP);
    if (t < 4 * BN) hist4[t] = 0;
    for (int j = t; j < nst; j += 1024) stage[j] = bpk[bstart + j];
    unsigned int ov[OVR];
    int nov = 0;
    for (int j = SCAP + t; j < len; j += 1024)
        if (nov < OVR) ov[nov++] = bpk[bstart + j];
    __syncthreads();
    int rep = (t & 3) << 8;
    for (int j = t; j < nst; j += 1024) atomicAdd(&hist4[rep | (stage[j] >> 17)], 1);
    for (int i = 0; i < nov; i++) atomicAdd(&hist4[rep | (ov[i] >> 17)], 1);
    __syncthreads();
    int hcount = 0;
    if (t < BN) {
        hcount = hist4[t] + hist4[BN + t] + hist4[2 * BN + t] + hist4[3 * BN + t];
        excl[t] = hcount;
    }
    __syncthreads();
    for (int off = 1; off < BN; off <<= 1) {
        int v = 0;
        if (t < BN && t >= off) v = excl[t - off];
        __syncthreads();
        if (t < BN && t >= off) excl[t] += v;
        __syncthreads();
    }
    if (t < BN) {
        int ex = excl[t] - hcount;
        cur[t] = ex;
        int node = (k << BSH) + t;
        rowptr[node] = bstart + ex;
        if (node < N) dinv[node] = 1.0f / sqrtf(1.0f + (float)hcount);
    }
    __syncthreads();
    for (int j = t; j < nst; j += 1024) {
        unsigned int ww = stage[j];
        int r = atomicAdd(&cur[ww >> 17], 1);
        bpk[bstart + r] = ww & 0x1FFFF;
    }
    for (int i = 0; i < nov; i++) {
        unsigned int ww = ov[i];
        int r = atomicAdd(&cur[ww >> 17], 1);
        bpk[bstart + r] = ww & 0x1FFFF;
    }
}

// ---------------- h1b = bf16( dinv * (x @ W1) ) ----------------------------
__global__ __launch_bounds__(256) void k_xw1(const float* __restrict__ x, const float* __restrict__ W1,
                                             const float* __restrict__ dinv,
                                             unsigned short* __restrict__ h1b, int N) {
    __shared__ float sWT[HID * WST];     // transposed + padded: [h][k], stride 132
    __shared__ float sx[16 * 132];
    int t = threadIdx.x;
    for (int i = t; i < HID * NFEAT; i += 256) {
        int h = i >> 7, kk = i & 127;
        sWT[h * WST + kk] = W1[kk * HID + h];
    }
    int local = t >> 4;
    int h     = t & 15;
    int n = blockIdx.x * 16 + local;
    if (n < N) {
        const float4* xr = (const float4*)(x + (size_t)n * NFEAT);
        float4 a = xr[h * 2];
        float4 b = xr[h * 2 + 1];
        float* sp = sx + local * 132 + h * 8;
        ((float4*)sp)[0] = a;
        ((float4*)sp)[1] = b;
    }
    __syncthreads();
    if (n >= N) return;
    const float4* xr4 = (const float4*)(sx + local * 132);
    const float4* wr4 = (const float4*)(sWT + h * WST);
    float acc = 0.0f;
    #pragma unroll
    for (int k4 = 0; k4 < 32; k4++) {
        float4 a = xr4[k4];
        float4 b = wr4[k4];
        acc += a.x * b.x + a.y * b.y + a.z * b.z + a.w * b.w;
    }
    h1b[(size_t)n * HID + h] = f2bf(acc * dinv[n]);   // coalesced 2B/lane
}

__device__ __forceinline__ void acc8(float* acc, ushortv8 v) {
    #pragma unroll
    for (int i = 0; i < 8; i++)
        acc[i] += __uint_as_float(((unsigned)v[i]) << 16);
}

// ---------------- gather1: CSR bf16 gather -> PReLU -> W2 -> t2s -----------
__global__ __launch_bounds__(256) void k_gather1(const int* __restrict__ esrc, const int* __restrict__ rowptr,
                                                 const unsigned short* __restrict__ h1b, const float* __restrict__ dinv,
                                                 const float* __restrict__ b1, const float* __restrict__ prelu_a,
                                                 const float* __restrict__ W2,
                                                 float* __restrict__ t2s, int N) {
    int t = threadIdx.x;
    int n = blockIdx.x * 128 + (t >> 1);
    int q = t & 1;
    if (n >= N) return;
    const ushortv8* h8 = (const ushortv8*)h1b;     // 16B granules; row n half q = n*2+q
    int r0 = rowptr[n];
    int r1 = rowptr[n + 1];
    float acc[8] = {0.f, 0.f, 0.f, 0.f, 0.f, 0.f, 0.f, 0.f};
    acc8(acc, h8[(size_t)n * 2 + q]);              // self-loop seed
    int i = r0;
    for (; i + 4 <= r1; i += 4) {
        int s0 = esrc[i], s1 = esrc[i + 1], s2 = esrc[i + 2], s3 = esrc[i + 3];
        ushortv8 v0 = h8[(size_t)s0 * 2 + q];
        ushortv8 v1 = h8[(size_t)s1 * 2 + q];
        ushortv8 v2 = h8[(size_t)s2 * 2 + q];
        ushortv8 v3 = h8[(size_t)s3 * 2 + q];
        acc8(acc, v0); acc8(acc, v1); acc8(acc, v2); acc8(acc, v3);
    }
    for (; i < r1; i++) acc8(acc, h8[(size_t)esrc[i] * 2 + q]);

    float di = dinv[n];
    float a = prelu_a[0];
    float o0 = 0.0f, o1 = 0.0f;
    #pragma unroll
    for (int j = 0; j < 8; j++) {
        int f = q * 8 + j;
        float tv = di * acc[j] + b1[f];
        tv = (tv >= 0.0f) ? tv : a * tv;
        o0 += tv * W2[f * 2 + 0];
        o1 += tv * W2[f * 2 + 1];
    }
    o0 += __shfl_xor(o0, 1);
    o1 += __shfl_xor(o1, 1);
    if (q == 0) {
        *(float2*)(t2s + (size_t)n * 2) = make_float2(di * o0, di * o1);
    }
}

// ---------------- gather2 + pool: CSR sum of t2s -> per-graph bins ---------
__global__ __launch_bounds__(256) void k_gather2(const int* __restrict__ esrc, const int* __restrict__ rowptr,
                                                 const float* __restrict__ t2s, const float* __restrict__ dinv,
                                                 const int* __restrict__ batch,
                                                 float* __restrict__ partials, int N) {
    __shared__ float pg[PSTRIDE];
    int t = threadIdx.x;
    if (t < PSTRIDE) pg[t] = 0.0f;
    __syncthreads();
    int n = blockIdx.x * 128 + (t >> 1);
    int c = t & 1;
    if (n < N) {
        int r0 = rowptr[n];
        int r1 = rowptr[n + 1];
        float val = t2s[(size_t)n * 2 + c];    // self-loop
        int i = r0;
        for (; i + 4 <= r1; i += 4) {
            int s0 = esrc[i], s1 = esrc[i + 1], s2 = esrc[i + 2], s3 = esrc[i + 3];
            float v0 = t2s[(size_t)s0 * 2 + c];
            float v1 = t2s[(size_t)s1 * 2 + c];
            float v2 = t2s[(size_t)s2 * 2 + c];
            float v3 = t2s[(size_t)s3 * 2 + c];
            val += (v0 + v1) + (v2 + v3);
        }
        for (; i < r1; i++) val += t2s[(size_t)esrc[i] * 2 + c];
        float dd = dinv[n];
        int g = batch[n];
        atomicAdd(&pg[g * 2 + c], dd * val);
        if (c == 0) atomicAdd(&pg[128 + g], 1.0f);
    }
    __syncthreads();
    if (t < PSTRIDE) partials[(size_t)blockIdx.x * PSTRIDE + t] = pg[t];
}

// ---------------- final: reduce partials, add bias, divide -----------------
__global__ __launch_bounds__(256) void k_final(const float* __restrict__ partials,
                                               const float* __restrict__ b2, float* __restrict__ out) {
    __shared__ float fs[PSTRIDE];
    int t = threadIdx.x;
    if (t < PSTRIDE) {
        float s0 = 0.0f, s1 = 0.0f, s2 = 0.0f, s3 = 0.0f;
        int r = 0;
        for (; r + 4 <= GB2; r += 4) {
            s0 += partials[(size_t)r * PSTRIDE + t];
            s1 += partials[(size_t)(r + 1) * PSTRIDE + t];
            s2 += partials[(size_t)(r + 2) * PSTRIDE + t];
            s3 += partials[(size_t)(r + 3) * PSTRIDE + t];
        }
        for (; r < GB2; r++) s0 += partials[(size_t)r * PSTRIDE + t];
        fs[t] = (s0 + s1) + (s2 + s3);
    }
    __syncthreads();
    if (t < NGRAPH * NOUT) {
        int g = t >> 1, c = t & 1;
        float cnt = fs[128 + g];
        out[t] = (fs[t] + cnt * b2[c]) / fmaxf(cnt, 1.0f);
    }
}

extern "C" void kernel_launch(void* const* d_in, const int* in_sizes, int n_in,
                              void* d_out, int out_size, void* d_ws, size_t ws_size,
                              hipStream_t stream) {
    const float* x       = (const float*)d_in[0];
    const float* W1      = (const float*)d_in[1];
    const float* b1      = (const float*)d_in[2];
    const float* prelu_a = (const float*)d_in[3];
    const float* W2      = (const float*)d_in[4];
    const float* b2      = (const float*)d_in[5];
    const int*   ei      = (const int*)d_in[6];
    const int*   batch   = (const int*)d_in[7];

    const int N = in_sizes[7];          // 100000
    const int E = in_sizes[6] / 2;      // 6400000
    const int* src = ei;
    const int* dst = ei + E;

    // workspace layout (4-byte units), ~31 MB total
    float* ws     = (float*)d_ws;
    float* dinv   = ws;                                        // 100352
    unsigned short* h1b = (unsigned short*)(dinv + 100352);    // 16N ushorts (= 8N floats)
    float* t2s    = dinv + 100352 + (size_t)N * HID / 2;       // 2N
    int*   rowptr = (int*)(t2s + (size_t)N * NOUT);            // 100352
    int*   gcnt   = rowptr + 100352;                           // GCNT_TOT (800 KB)
    unsigned int* bpk = (unsigned int*)(gcnt + GCNT_TOT);      // E (becomes esrc)
    float* partials = (float*)(bpk + E);                       // GB2*PSTRIDE
    int*   bsum   = (int*)(partials + (size_t)GB2 * PSTRIDE);  // SCAN_NB

    float* out = (float*)d_out;

    k_count<<<NCB, 1024, 0, stream>>>(dst, gcnt, E);
    k_scan1<<<SCAN_NB, 1024, 0, stream>>>(gcnt, bsum);
    k_scan2<<<1, 256, 0, stream>>>(bsum);
    k_scan3<<<SCAN_NB, 1024, 0, stream>>>(gcnt, bsum);
    k_scatter<<<NCB, 1024, 0, stream>>>(src, dst, gcnt, bpk, E);
    k_sort<<<NBUCK, 1024, 0, stream>>>(bpk, gcnt, rowptr, dinv, E, N);
    k_xw1<<<(N + 15) / 16, 256, 0, stream>>>(x, W1, dinv, h1b, N);
    k_gather1<<<(N + 127) / 128, 256, 0, stream>>>((const int*)bpk, rowptr, h1b, dinv, b1, prelu_a, W2, t2s, N);
    k_gather2<<<GB2, 256, 0, stream>>>((const int*)bpk, rowptr, t2s, dinv, batch, partials, N);
    k_final<<<1, 256, 0, stream>>>(partials, b2, out);
}

// Round 12
// 342.139 us; speedup vs baseline: 1.3095x; 1.0117x over previous
//
#include <hip/hip_runtime.h>

#define NFEAT 128
#define HID 16
#define NOUT 2
#define NGRAPH 64

#define BSH 8                      // bucket shift: 256 nodes/bucket
#define BN 256                     // nodes per bucket
#define NBUCK 391                  // ceil(100000/256)
#define NCB 512                    // count/scatter chunks (1024-thr blocks, 2/CU)
#define CH 12500                   // chunk length = E/NCB exactly
#define EPT 13                     // edges per thread (13*1024 >= 12500)
#define GCNT_TOT (NBUCK * NCB)     // 200192
#define SCAN_NB 196                // scan blocks: 196*1024 >= GCNT_TOT
#define SCAP 18176                 // k_sort staged edges per bucket (71 KB)
#define OVR 8                      // k_sort register overflow slots/thread
#define PSTRIDE 192                // 128 graph sums + 64 counts
#define GB2 1563                   // gather blocks = ceil(100000/64)
#define WST 132                    // sWT row stride (floats): 128+4 pad

typedef unsigned short ushortv8 __attribute__((ext_vector_type(8)));

// XCD-aware chunk remap: consecutive chunks stay on one XCD (8 XCDs, rr dispatch)
__device__ __forceinline__ int chunk_id(int bid) { return ((bid & 7) << 6) | (bid >> 3); }

// RNE float -> bf16 bits
__device__ __forceinline__ unsigned short f2bf(float f) {
    unsigned u = __float_as_uint(f);
    return (unsigned short)((u + 0x7FFFu + ((u >> 16) & 1u)) >> 16);
}

// ---------------- count: per-(bucket, chunk) histogram ---------------------
__global__ __launch_bounds__(1024) void k_count(const int* __restrict__ dst, int* __restrict__ gcnt, int E) {
    __shared__ int c[NBUCK];
    int t = threadIdx.x;
    int cid = chunk_id(blockIdx.x);
    for (int i = t; i < NBUCK; i += 1024) c[i] = 0;
    __syncthreads();
    int start = cid * CH;
    int end = min(E, start + CH);
    for (int e = start + t; e < end; e += 1024)
        atomicAdd(&c[dst[e] >> BSH], 1);
    __syncthreads();
    for (int i = t; i < NBUCK; i += 1024) gcnt[i * NCB + cid] = c[i];
}

// ---------------- scan stage 1: block-local exclusive scan + block sums ----
__global__ __launch_bounds__(1024) void k_scan1(int* __restrict__ gcnt, int* __restrict__ bsum) {
    __shared__ int sh[1024];
    int t = threadIdx.x;
    int idx = blockIdx.x * 1024 + t;
    int v = (idx < GCNT_TOT) ? gcnt[idx] : 0;
    sh[t] = v;
    __syncthreads();
    for (int off = 1; off < 1024; off <<= 1) {
        int a = sh[t];
        int b = (t >= off) ? sh[t - off] : 0;
        __syncthreads();
        sh[t] = a + b;
        __syncthreads();
    }
    if (idx < GCNT_TOT) gcnt[idx] = sh[t] - v;     // exclusive within block
    if (t == 1023) bsum[blockIdx.x] = sh[1023];
}

// ---------------- scan stage 2: scan the 196 block sums --------------------
__global__ __launch_bounds__(256) void k_scan2(int* __restrict__ bsum) {
    __shared__ int sh[256];
    int t = threadIdx.x;
    int v = (t < SCAN_NB) ? bsum[t] : 0;
    sh[t] = v;
    __syncthreads();
    for (int off = 1; off < 256; off <<= 1) {
        int a = sh[t];
        int b = (t >= off) ? sh[t - off] : 0;
        __syncthreads();
        sh[t] = a + b;
        __syncthreads();
    }
    if (t < SCAN_NB) bsum[t] = sh[t] - v;          // exclusive
}

// ---------------- scan stage 3: add block offsets --------------------------
__global__ __launch_bounds__(1024) void k_scan3(int* __restrict__ gcnt, const int* __restrict__ bsum) {
    int idx = blockIdx.x * 1024 + threadIdx.x;
    if (idx < GCNT_TOT) gcnt[idx] += bsum[blockIdx.x];
}

// ---------------- scatter: LDS-staged local sort by bucket, burst flush ----
__global__ __launch_bounds__(1024) void k_scatter(const int* __restrict__ src, const int* __restrict__ dst,
                                                  const int* __restrict__ gcnt,
                                                  unsigned int* __restrict__ bpk, int E) {
    __shared__ unsigned int stage[CH + 44];  // 50176 B
    __shared__ int hist4[4 * NBUCK];         // 6256 B
    __shared__ int scan[512];                // 2048 B
    __shared__ int excl[NBUCK + 1];
    __shared__ int cur[NBUCK];
    int t = threadIdx.x;
    int cid = chunk_id(blockIdx.x);
    int start = cid * CH;
    int end = min(E, start + CH);
    for (int i = t; i < 4 * NBUCK; i += 1024) hist4[i] = 0;
    __syncthreads();

    // phase 1: load into registers, histogram
    unsigned int w[EPT];
    int kb[EPT];
    int rep = (t & 3) * NBUCK;
    #pragma unroll
    for (int i = 0; i < EPT; i++) {
        int e = start + i * 1024 + t;
        kb[i] = -1;
        if (e < end) {
            int s = src[e];
            int d = dst[e];
            int b = d >> BSH;
            kb[i] = b;
            w[i] = ((unsigned)(d & (BN - 1)) << 17) | (unsigned)s;
            atomicAdd(&hist4[rep + b], 1);
        }
    }
    __syncthreads();

    // phase 2: scan 391 bucket counts (512-wide Hillis-Steele)
    int hc = 0;
    if (t < NBUCK) hc = hist4[t] + hist4[NBUCK + t] + hist4[2 * NBUCK + t] + hist4[3 * NBUCK + t];
    if (t < 512) scan[t] = (t < NBUCK) ? hc : 0;
    __syncthreads();
    for (int off = 1; off < 512; off <<= 1) {
        int a = 0;
        if (t < 512 && t >= off) a = scan[t - off];
        __syncthreads();
        if (t < 512 && t >= off) scan[t] += a;
        __syncthreads();
    }
    if (t < NBUCK) {
        int ex = scan[t] - hc;
        excl[t] = ex;
        cur[t] = ex;
    }
    if (t == 0) excl[NBUCK] = end - start;
    __syncthreads();

    // phase 3: rank into bucket-ordered LDS stage
    #pragma unroll
    for (int i = 0; i < EPT; i++) {
        if (kb[i] >= 0) {
            int r = atomicAdd(&cur[kb[i]], 1);
            stage[r] = w[i];
        }
    }
    __syncthreads();

    // phase 4: burst flush, one wave per bucket run (contiguous global writes)
    int wave = t >> 6, lane = t & 63;
    for (int b = wave; b < NBUCK; b += 16) {
        int s0 = excl[b], s1 = excl[b + 1];
        int gbase = gcnt[b * NCB + cid];
        for (int j = s0 + lane; j < s1; j += 64)
            bpk[gbase + (j - s0)] = stage[j];
    }
}

// ---------------- sort: per-bucket counting sort (in place) -> CSR ---------
__global__ __launch_bounds__(1024) void k_sort(unsigned int* __restrict__ bpk, const int* __restrict__ gcnt,
                                               int* __restrict__ rowptr, float* __restrict__ dinv, int E, int N) {
    __shared__ unsigned int stage[SCAP];     // 71 KB
    __shared__ int hist4[4 * BN];            // x4 replicated histogram
    __shared__ int excl[BN], cur[BN];
    int t = threadIdx.x;
    int k = blockIdx.x;
    int bstart = gcnt[k * NCB];
    int bend = (k < NBUCK - 1) ? gcnt[(k + 1) * NCB] : E;
    int len = bend - bstart;
    int nst = min(len, SCAP);
    if (t < 4 * BN) hist4[t] = 0;
    for (int j = t; j < nst; j += 1024) stage[j] = bpk[bstart + j];
    unsigned int ov[OVR];
    int nov = 0;
    for (int j = SCAP + t; j < len; j += 1024)
        if (nov < OVR) ov[nov++] = bpk[bstart + j];
    __syncthreads();
    int rep = (t & 3) << 8;
    for (int j = t; j < nst; j += 1024) atomicAdd(&hist4[rep | (stage[j] >> 17)], 1);
    for (int i = 0; i < nov; i++) atomicAdd(&hist4[rep | (ov[i] >> 17)], 1);
    __syncthreads();
    int hcount = 0;
    if (t < BN) {
        hcount = hist4[t] + hist4[BN + t] + hist4[2 * BN + t] + hist4[3 * BN + t];
        excl[t] = hcount;
    }
    __syncthreads();
    for (int off = 1; off < BN; off <<= 1) {
        int v = 0;
        if (t < BN && t >= off) v = excl[t - off];
        __syncthreads();
        if (t < BN && t >= off) excl[t] += v;
        __syncthreads();
    }
    if (t < BN) {
        int ex = excl[t] - hcount;
        cur[t] = ex;
        int node = (k << BSH) + t;
        rowptr[node] = bstart + ex;
        if (node < N) dinv[node] = 1.0f / sqrtf(1.0f + (float)hcount);
    }
    __syncthreads();
    for (int j = t; j < nst; j += 1024) {
        unsigned int ww = stage[j];
        int r = atomicAdd(&cur[ww >> 17], 1);
        bpk[bstart + r] = ww & 0x1FFFF;
    }
    for (int i = 0; i < nov; i++) {
        unsigned int ww = ov[i];
        int r = atomicAdd(&cur[ww >> 17], 1);
        bpk[bstart + r] = ww & 0x1FFFF;
    }
}

// ---------------- h1b = bf16( dinv * (x @ W1) ) ----------------------------
__global__ __launch_bounds__(256) void k_xw1(const float* __restrict__ x, const float* __restrict__ W1,
                                             const float* __restrict__ dinv,
                                             unsigned short* __restrict__ h1b, int N) {
    __shared__ float sWT[HID * WST];     // transposed + padded: [h][k], stride 132
    __shared__ float sx[16 * 132];
    int t = threadIdx.x;
    for (int i = t; i < HID * NFEAT; i += 256) {
        int h = i >> 7, kk = i & 127;
        sWT[h * WST + kk] = W1[kk * HID + h];
    }
    int local = t >> 4;
    int h     = t & 15;
    int n = blockIdx.x * 16 + local;
    if (n < N) {
        const float4* xr = (const float4*)(x + (size_t)n * NFEAT);
        float4 a = xr[h * 2];
        float4 b = xr[h * 2 + 1];
        float* sp = sx + local * 132 + h * 8;
        ((float4*)sp)[0] = a;
        ((float4*)sp)[1] = b;
    }
    __syncthreads();
    if (n >= N) return;
    const float4* xr4 = (const float4*)(sx + local * 132);
    const float4* wr4 = (const float4*)(sWT + h * WST);
    float acc = 0.0f;
    #pragma unroll
    for (int k4 = 0; k4 < 32; k4++) {
        float4 a = xr4[k4];
        float4 b = wr4[k4];
        acc += a.x * b.x + a.y * b.y + a.z * b.z + a.w * b.w;
    }
    h1b[(size_t)n * HID + h] = f2bf(acc * dinv[n]);   // coalesced 2B/lane
}

__device__ __forceinline__ void acc8(float* acc, ushortv8 v) {
    #pragma unroll
    for (int i = 0; i < 8; i++)
        acc[i] += __uint_as_float(((unsigned)v[i]) << 16);
}

// ---------------- gather1: CSR bf16 gather -> PReLU -> W2 -> t2s -----------
// 4 lanes/node: q = feature half (16B), hf = edge half; 2x waves vs round 11
__global__ __launch_bounds__(256) void k_gather1(const int* __restrict__ esrc, const int* __restrict__ rowptr,
                                                 const unsigned short* __restrict__ h1b, const float* __restrict__ dinv,
                                                 const float* __restrict__ b1, const float* __restrict__ prelu_a,
                                                 const float* __restrict__ W2,
                                                 float* __restrict__ t2s, int N) {
    int t = threadIdx.x;
    int n = blockIdx.x * 64 + (t >> 2);
    int q = t & 1;
    int hf = (t >> 1) & 1;
    if (n >= N) return;
    const ushortv8* h8 = (const ushortv8*)h1b;
    int r0 = rowptr[n];
    int r1 = rowptr[n + 1];
    int mid = (r0 + r1) >> 1;
    int es = hf ? mid : r0;
    int ee = hf ? r1 : mid;
    float acc[8] = {0.f, 0.f, 0.f, 0.f, 0.f, 0.f, 0.f, 0.f};
    if (hf == 0) acc8(acc, h8[(size_t)n * 2 + q]);   // self-loop seed
    int i = es;
    for (; i + 4 <= ee; i += 4) {
        int s0 = esrc[i], s1 = esrc[i + 1], s2 = esrc[i + 2], s3 = esrc[i + 3];
        ushortv8 v0 = h8[(size_t)s0 * 2 + q];
        ushortv8 v1 = h8[(size_t)s1 * 2 + q];
        ushortv8 v2 = h8[(size_t)s2 * 2 + q];
        ushortv8 v3 = h8[(size_t)s3 * 2 + q];
        acc8(acc, v0); acc8(acc, v1); acc8(acc, v2); acc8(acc, v3);
    }
    for (; i < ee; i++) acc8(acc, h8[(size_t)esrc[i] * 2 + q]);

    // combine edge halves (lane pairs differing in bit 1)
    #pragma unroll
    for (int j = 0; j < 8; j++) acc[j] += __shfl_xor(acc[j], 2);

    if (hf != 0) return;
    float di = dinv[n];
    float a = prelu_a[0];
    float o0 = 0.0f, o1 = 0.0f;
    #pragma unroll
    for (int j = 0; j < 8; j++) {
        int f = q * 8 + j;
        float tv = di * acc[j] + b1[f];
        tv = (tv >= 0.0f) ? tv : a * tv;
        o0 += tv * W2[f * 2 + 0];
        o1 += tv * W2[f * 2 + 1];
    }
    o0 += __shfl_xor(o0, 1);
    o1 += __shfl_xor(o1, 1);
    if (q == 0) {
        *(float2*)(t2s + (size_t)n * 2) = make_float2(di * o0, di * o1);
    }
}

// ---------------- gather2 + pool: CSR sum of t2s -> per-graph bins ---------
// 4 lanes/node: c = component, hf = edge half
__global__ __launch_bounds__(256) void k_gather2(const int* __restrict__ esrc, const int* __restrict__ rowptr,
                                                 const float* __restrict__ t2s, const float* __restrict__ dinv,
                                                 const int* __restrict__ batch,
                                                 float* __restrict__ partials, int N) {
    __shared__ float pg[PSTRIDE];
    int t = threadIdx.x;
    if (t < PSTRIDE) pg[t] = 0.0f;
    __syncthreads();
    int n = blockIdx.x * 64 + (t >> 2);
    int c = t & 1;
    int hf = (t >> 1) & 1;
    if (n < N) {
        int r0 = rowptr[n];
        int r1 = rowptr[n + 1];
        int mid = (r0 + r1) >> 1;
        int es = hf ? mid : r0;
        int ee = hf ? r1 : mid;
        float val = (hf == 0) ? t2s[(size_t)n * 2 + c] : 0.0f;   // self-loop
        int i = es;
        for (; i + 4 <= ee; i += 4) {
            int s0 = esrc[i], s1 = esrc[i + 1], s2 = esrc[i + 2], s3 = esrc[i + 3];
            float v0 = t2s[(size_t)s0 * 2 + c];
            float v1 = t2s[(size_t)s1 * 2 + c];
            float v2 = t2s[(size_t)s2 * 2 + c];
            float v3 = t2s[(size_t)s3 * 2 + c];
            val += (v0 + v1) + (v2 + v3);
        }
        for (; i < ee; i++) val += t2s[(size_t)esrc[i] * 2 + c];
        val += __shfl_xor(val, 2);
        if (hf == 0) {
            float dd = dinv[n];
            int g = batch[n];
            atomicAdd(&pg[g * 2 + c], dd * val);
            if (c == 0) atomicAdd(&pg[128 + g], 1.0f);
        }
    }
    __syncthreads();
    if (t < PSTRIDE) partials[(size_t)blockIdx.x * PSTRIDE + t] = pg[t];
}

// ---------------- final: reduce partials, add bias, divide -----------------
__global__ __launch_bounds__(256) void k_final(const float* __restrict__ partials,
                                               const float* __restrict__ b2, float* __restrict__ out) {
    __shared__ float fs[PSTRIDE];
    int t = threadIdx.x;
    if (t < PSTRIDE) {
        float s0 = 0.0f, s1 = 0.0f, s2 = 0.0f, s3 = 0.0f;
        int r = 0;
        for (; r + 4 <= GB2; r += 4) {
            s0 += partials[(size_t)r * PSTRIDE + t];
            s1 += partials[(size_t)(r + 1) * PSTRIDE + t];
            s2 += partials[(size_t)(r + 2) * PSTRIDE + t];
            s3 += partials[(size_t)(r + 3) * PSTRIDE + t];
        }
        for (; r < GB2; r++) s0 += partials[(size_t)r * PSTRIDE + t];
        fs[t] = (s0 + s1) + (s2 + s3);
    }
    __syncthreads();
    if (t < NGRAPH * NOUT) {
        int g = t >> 1, c = t & 1;
        float cnt = fs[128 + g];
        out[t] = (fs[t] + cnt * b2[c]) / fmaxf(cnt, 1.0f);
    }
}

extern "C" void kernel_launch(void* const* d_in, const int* in_sizes, int n_in,
                              void* d_out, int out_size, void* d_ws, size_t ws_size,
                              hipStream_t stream) {
    const float* x       = (const float*)d_in[0];
    const float* W1      = (const float*)d_in[1];
    const float* b1      = (const float*)d_in[2];
    const float* prelu_a = (const float*)d_in[3];
    const float* W2      = (const float*)d_in[4];
    const float* b2      = (const float*)d_in[5];
    const int*   ei      = (const int*)d_in[6];
    const int*   batch   = (const int*)d_in[7];

    const int N = in_sizes[7];          // 100000
    const int E = in_sizes[6] / 2;      // 6400000
    const int* src = ei;
    const int* dst = ei + E;

    // workspace layout (4-byte units), ~32 MB total
    float* ws     = (float*)d_ws;
    float* dinv   = ws;                                        // 100352
    unsigned short* h1b = (unsigned short*)(dinv + 100352);    // 16N ushorts (= 8N floats)
    float* t2s    = dinv + 100352 + (size_t)N * HID / 2;       // 2N
    int*   rowptr = (int*)(t2s + (size_t)N * NOUT);            // 100352
    int*   gcnt   = rowptr + 100352;                           // GCNT_TOT (800 KB)
    unsigned int* bpk = (unsigned int*)(gcnt + GCNT_TOT);      // E (becomes esrc)
    float* partials = (float*)(bpk + E);                       // GB2*PSTRIDE
    int*   bsum   = (int*)(partials + (size_t)GB2 * PSTRIDE);  // SCAN_NB

    float* out = (float*)d_out;

    k_count<<<NCB, 1024, 0, stream>>>(dst, gcnt, E);
    k_scan1<<<SCAN_NB, 1024, 0, stream>>>(gcnt, bsum);
    k_scan2<<<1, 256, 0, stream>>>(bsum);
    k_scan3<<<SCAN_NB, 1024, 0, stream>>>(gcnt, bsum);
    k_scatter<<<NCB, 1024, 0, stream>>>(src, dst, gcnt, bpk, E);
    k_sort<<<NBUCK, 1024, 0, stream>>>(bpk, gcnt, rowptr, dinv, E, N);
    k_xw1<<<(N + 15) / 16, 256, 0, stream>>>(x, W1, dinv, h1b, N);
    k_gather1<<<GB2, 256, 0, stream>>>((const int*)bpk, rowptr, h1b, dinv, b1, prelu_a, W2, t2s, N);
    k_gather2<<<GB2, 256, 0, stream>>>((const int*)bpk, rowptr, t2s, dinv, batch, partials, N);
    k_final<<<1, 256, 0, stream>>>(partials, b2, out);
}